// Round 1
// baseline (236.620 us; speedup 1.0000x reference)
//
#include <hip/hip_runtime.h>
#include <hip/hip_bf16.h>

typedef unsigned short u16;

#define BATCH 8
#define CIN 512
#define COUT 512
#define SDIM 512
#define RES 64
#define PIX (RES * RES)          // 4096

__device__ __constant__ static const float kAffScale  = 0.04419417382415922f;   // 1/sqrt(512)
__device__ __constant__ static const float kConvScale = 0.014731391274719742f;  // 1/sqrt(512*9)
__device__ __constant__ static const float kGain      = 1.4142135623730951f;    // sqrt(2)

typedef __bf16 bf16x8 __attribute__((ext_vector_type(8)));
typedef float  f32x4  __attribute__((ext_vector_type(4)));

// ---------------------------------------------------------------------------
// Kernel 1: style[b][c] = (w[b] . affine_w[c]) * AFF_SCALE + affine_b[c]
// Also zeroes the 256B zero-pad scratch buffer.
// ---------------------------------------------------------------------------
__global__ void style_k(const float* __restrict__ w, const float* __restrict__ aw,
                        const float* __restrict__ ab, float* __restrict__ style,
                        float* __restrict__ zbuf) {
  int tid = blockIdx.x * 256 + threadIdx.x;      // 0..4095
  if (blockIdx.x == 0 && threadIdx.x < 64) zbuf[threadIdx.x] = 0.0f;
  int b = tid >> 9, c = tid & 511;
  const float* wp = w + b * SDIM;
  const float* ap = aw + c * SDIM;
  float s = 0.0f;
  for (int k = 0; k < SDIM; ++k) s += wp[k] * ap[k];
  style[tid] = s * kAffScale + ab[c];
}

// ---------------------------------------------------------------------------
// Kernel 2: cw2[o][i] = sum_t conv_w[o][i][t]^2
// ---------------------------------------------------------------------------
__global__ void cw2_k(const float* __restrict__ cw, float* __restrict__ cw2) {
  int tid = blockIdx.x * 256 + threadIdx.x;      // 0..262143 == o*512+i
  const float* p = cw + tid * 9;
  float s = 0.0f;
  #pragma unroll
  for (int t = 0; t < 9; ++t) { float v = p[t]; s += v * v; }
  cw2[tid] = s;
}

// ---------------------------------------------------------------------------
// Kernel 3: fac[b][o] = CONV_SCALE * rsqrt(CONV_SCALE^2 * sum_i style^2*cw2 + 1e-8)
// One wave per (b,o).
// ---------------------------------------------------------------------------
__global__ void fac_k(const float* __restrict__ style, const float* __restrict__ cw2,
                      float* __restrict__ fac) {
  int wid  = blockIdx.x * 4 + (threadIdx.x >> 6); // 0..4095
  int lane = threadIdx.x & 63;
  int b = wid >> 9, o = wid & 511;
  const float* st = style + b * CIN;
  const float* c2 = cw2 + o * CIN;
  float s = 0.0f;
  for (int i = lane; i < CIN; i += 64) { float sv = st[i]; s += sv * sv * c2[i]; }
  #pragma unroll
  for (int off = 32; off; off >>= 1) s += __shfl_xor(s, off);
  if (lane == 0) {
    float d = rsqrtf(s * kConvScale * kConvScale + 1e-8f);
    fac[wid] = d * kConvScale;
  }
}

// ---------------------------------------------------------------------------
// Kernel 4: wb[t][o][i] = bf16(conv_w[o][i][t])   (K-contiguous A operand)
// ---------------------------------------------------------------------------
__global__ void wcast_k(const float* __restrict__ cw, u16* __restrict__ wb) {
  int tid = blockIdx.x * 256 + threadIdx.x;      // o*512+i
  int o = tid >> 9, i = tid & 511;
  const float* p = cw + tid * 9;
  #pragma unroll
  for (int t = 0; t < 9; ++t) {
    __hip_bfloat16 h = __float2bfloat16(p[t]);
    wb[(t * COUT + o) * CIN + i] = *(u16*)&h;
  }
}

// ---------------------------------------------------------------------------
// Kernel 5: xs[b][pix][i] = bf16(x[b][i][pix] * style[b][i])   (NHWC transpose)
// 64x64 tile transpose through LDS, both phases coalesced.
// ---------------------------------------------------------------------------
__global__ void modx_k(const float* __restrict__ x, const float* __restrict__ style,
                       u16* __restrict__ xs) {
  __shared__ float t[64][65];
  int b  = blockIdx.z;
  int it = blockIdx.y * 64;                      // cin tile base
  int pt = blockIdx.x * 64;                      // pixel tile base
  int tp = threadIdx.x & 63;
  int tr = threadIdx.x >> 6;                     // 0..3
  for (int r = tr; r < 64; r += 4) {
    int i = it + r;
    t[r][tp] = x[(b * CIN + i) * PIX + pt + tp] * style[b * CIN + i];
  }
  __syncthreads();
  for (int r = tr; r < 64; r += 4) {
    __hip_bfloat16 h = __float2bfloat16(t[tp][r]);
    xs[(size_t)(b * PIX + pt + r) * CIN + it + tp] = *(u16*)&h;
  }
}

// ---------------------------------------------------------------------------
// Kernel 6: implicit-GEMM conv, M=COUT tile 128, N=pixels tile 128, BK=64,
// 9 taps x 8 k-steps. 4 waves (2x2), each 64x64 out via 4x4 16x16x32 MFMA.
// Double-buffered LDS, global_load_lds(16B), XOR swizzle slot^=(row&7).
// ---------------------------------------------------------------------------
__launch_bounds__(256, 2)
__global__ void gemm_k(const u16* __restrict__ wb, const u16* __restrict__ xs,
                       const float* __restrict__ fac, const float* __restrict__ noise,
                       const float* __restrict__ nscale_p, const float* __restrict__ bias,
                       const float* __restrict__ zbuf, float* __restrict__ y) {
  __shared__ __align__(16) u16 Abuf[2][128 * 64];  // [cout_local][cin 64] rows of 128B
  __shared__ __align__(16) u16 Bbuf[2][128 * 64];  // [pix_local][cin 64]

  const int tid = threadIdx.x;
  const int mt = blockIdx.x & 3;                 // cout tile (4)
  const int nt = blockIdx.x >> 2;                // 0..255 pixel tile
  const int b = nt >> 5;
  const int pbase = (nt & 31) * 128;             // pixel base within image
  const int hbase = pbase >> 6;

  const int lane = tid & 63;
  const int wv = tid >> 6;
  const int wm = wv >> 1, wn = wv & 1;           // 2x2 wave grid
  const int l15 = lane & 15, l4 = lane >> 4;

  f32x4 acc[4][4];
  #pragma unroll
  for (int i = 0; i < 4; ++i)
    #pragma unroll
    for (int j = 0; j < 4; ++j) acc[i][j] = (f32x4){0.f, 0.f, 0.f, 0.f};

  auto stage = [&](int kk, int buf) {
    const int t  = kk >> 3;                      // tap 0..8
    const int i0 = (kk & 7) << 6;                // cin base
    const int dy = t / 3 - 1, dx = t % 3 - 1;
    const u16* wsrc = wb + (size_t)(t * COUT + mt * 128) * CIN + i0;
    #pragma unroll
    for (int p = 0; p < 4; ++p) {
      int c = p * 256 + tid;                     // chunk 0..1023 (16B each)
      int row = c >> 3, slot = c & 7;
      int sg = slot ^ (row & 7);                 // pre-swizzled source slot
      const u16* src = wsrc + row * CIN + sg * 8;
      __builtin_amdgcn_global_load_lds(
          (const __attribute__((address_space(1))) void*)src,
          (__attribute__((address_space(3))) void*)(&Abuf[buf][c * 8]), 16, 0, 0);
    }
    #pragma unroll
    for (int p = 0; p < 4; ++p) {
      int c = p * 256 + tid;
      int row = c >> 3, slot = c & 7;
      int sg = slot ^ (row & 7);
      int hh = hbase + (row >> 6) + dy;
      int ww = (row & 63) + dx;
      const u16* src;
      if (hh < 0 || hh > 63 || ww < 0 || ww > 63)
        src = (const u16*)zbuf;                  // zero padding
      else
        src = xs + (size_t)((b * PIX + hh * 64 + ww)) * CIN + i0 + sg * 8;
      __builtin_amdgcn_global_load_lds(
          (const __attribute__((address_space(1))) void*)src,
          (__attribute__((address_space(3))) void*)(&Bbuf[buf][c * 8]), 16, 0, 0);
    }
  };

  stage(0, 0);
  __syncthreads();

  for (int kk = 0; kk < 72; ++kk) {
    const int cur = kk & 1;
    if (kk < 71) stage(kk + 1, cur ^ 1);
    #pragma unroll
    for (int kh = 0; kh < 2; ++kh) {
      bf16x8 af[4], bfr[4];
      #pragma unroll
      for (int mi = 0; mi < 4; ++mi) {
        int row = wm * 64 + mi * 16 + l15;
        int slot = (kh * 4 + l4) ^ (row & 7);
        af[mi] = *(const bf16x8*)&Abuf[cur][row * 64 + slot * 8];
      }
      #pragma unroll
      for (int ni = 0; ni < 4; ++ni) {
        int row = wn * 64 + ni * 16 + l15;
        int slot = (kh * 4 + l4) ^ (row & 7);
        bfr[ni] = *(const bf16x8*)&Bbuf[cur][row * 64 + slot * 8];
      }
      #pragma unroll
      for (int mi = 0; mi < 4; ++mi)
        #pragma unroll
        for (int ni = 0; ni < 4; ++ni)
          acc[mi][ni] = __builtin_amdgcn_mfma_f32_16x16x32_bf16(af[mi], bfr[ni],
                                                                acc[mi][ni], 0, 0, 0);
    }
    __syncthreads();
  }

  // Epilogue: y = lrelu(acc*fac + noise*nscale + bias) * sqrt(2)
  const float nscale = nscale_p[0];
  float nz[4];
  #pragma unroll
  for (int ni = 0; ni < 4; ++ni) {
    int n = pbase + wn * 64 + ni * 16 + l15;
    nz[ni] = noise[b * PIX + n] * nscale;
  }
  #pragma unroll
  for (int mi = 0; mi < 4; ++mi) {
    #pragma unroll
    for (int r = 0; r < 4; ++r) {
      int o = mt * 128 + wm * 64 + mi * 16 + l4 * 4 + r;
      float fv = fac[b * COUT + o];
      float bv = bias[o];
      float* yp = y + (size_t)(b * COUT + o) * PIX + pbase + wn * 64 + l15;
      #pragma unroll
      for (int ni = 0; ni < 4; ++ni) {
        float v = acc[mi][ni][r] * fv + nz[ni] + bv;
        v = (v > 0.0f ? v : 0.2f * v) * kGain;
        yp[ni * 16] = v;
      }
    }
  }
}

// ---------------------------------------------------------------------------
extern "C" void kernel_launch(void* const* d_in, const int* in_sizes, int n_in,
                              void* d_out, int out_size, void* d_ws, size_t ws_size,
                              hipStream_t stream) {
  const float* x      = (const float*)d_in[0];
  const float* w      = (const float*)d_in[1];
  const float* noise  = (const float*)d_in[2];
  const float* aff_w  = (const float*)d_in[3];
  const float* aff_b  = (const float*)d_in[4];
  const float* conv_w = (const float*)d_in[5];
  const float* nscale = (const float*)d_in[6];
  const float* bias   = (const float*)d_in[7];
  float* y = (float*)d_out;

  char* ws = (char*)d_ws;
  float* style = (float*)(ws);                          // 16 KB
  float* fac   = (float*)(ws + 16384);                  // 16 KB
  float* cw2   = (float*)(ws + 32768);                  // 1 MB
  float* zbuf  = (float*)(ws + 1081344);                // 256 B zeros
  u16*   wb    = (u16*)(ws + 1081600);                  // 9*512*512*2 = 4.5 MB
  u16*   xs    = (u16*)(ws + 5800192);                  // 8*4096*512*2 = 32 MB
  // total ws use: ~39.4 MB

  style_k<<<16, 256, 0, stream>>>(w, aff_w, aff_b, style, zbuf);
  cw2_k<<<1024, 256, 0, stream>>>(conv_w, cw2);
  fac_k<<<1024, 256, 0, stream>>>(style, cw2, fac);
  wcast_k<<<1024, 256, 0, stream>>>(conv_w, wb);
  modx_k<<<dim3(64, 8, 8), 256, 0, stream>>>(x, style, xs);
  gemm_k<<<1024, 256, 0, stream>>>(wb, xs, fac, noise, nscale, bias, zbuf, y);
}

// Round 2
// 232.266 us; speedup vs baseline: 1.0187x; 1.0187x over previous
//
#include <hip/hip_runtime.h>
#include <hip/hip_bf16.h>

typedef unsigned short u16;

#define BATCH 8
#define CIN 512
#define COUT 512
#define SDIM 512
#define RES 64
#define PIX (RES * RES)          // 4096

__device__ __constant__ static const float kAffScale  = 0.04419417382415922f;   // 1/sqrt(512)
__device__ __constant__ static const float kConvScale = 0.014731391274719742f;  // 1/sqrt(512*9)
__device__ __constant__ static const float kGain      = 1.4142135623730951f;    // sqrt(2)

typedef __bf16 bf16x8 __attribute__((ext_vector_type(8)));
typedef float  f32x4  __attribute__((ext_vector_type(4)));

// ---------------------------------------------------------------------------
// Kernel 1: style[b][c] = (w[b] . affine_w[c]) * AFF_SCALE + affine_b[c]
// ---------------------------------------------------------------------------
__global__ void style_k(const float* __restrict__ w, const float* __restrict__ aw,
                        const float* __restrict__ ab, float* __restrict__ style,
                        float* __restrict__ zbuf) {
  int tid = blockIdx.x * 256 + threadIdx.x;      // 0..4095
  if (blockIdx.x == 0 && threadIdx.x < 64) zbuf[threadIdx.x] = 0.0f;
  int b = tid >> 9, c = tid & 511;
  const float* wp = w + b * SDIM;
  const float* ap = aw + c * SDIM;
  float s = 0.0f;
  for (int k = 0; k < SDIM; ++k) s += wp[k] * ap[k];
  style[tid] = s * kAffScale + ab[c];
}

// ---------------------------------------------------------------------------
// Kernel 2: cw2[o][i] = sum_t conv_w[o][i][t]^2
// ---------------------------------------------------------------------------
__global__ void cw2_k(const float* __restrict__ cw, float* __restrict__ cw2) {
  int tid = blockIdx.x * 256 + threadIdx.x;      // o*512+i
  const float* p = cw + tid * 9;
  float s = 0.0f;
  #pragma unroll
  for (int t = 0; t < 9; ++t) { float v = p[t]; s += v * v; }
  cw2[tid] = s;
}

// ---------------------------------------------------------------------------
// Kernel 3: fac[b][o] = CONV_SCALE * rsqrt(CONV_SCALE^2 * sum_i style^2*cw2 + 1e-8)
// ---------------------------------------------------------------------------
__global__ void fac_k(const float* __restrict__ style, const float* __restrict__ cw2,
                      float* __restrict__ fac) {
  int wid  = blockIdx.x * 4 + (threadIdx.x >> 6); // 0..4095
  int lane = threadIdx.x & 63;
  int b = wid >> 9, o = wid & 511;
  const float* st = style + b * CIN;
  const float* c2 = cw2 + o * CIN;
  float s = 0.0f;
  for (int i = lane; i < CIN; i += 64) { float sv = st[i]; s += sv * sv * c2[i]; }
  #pragma unroll
  for (int off = 32; off; off >>= 1) s += __shfl_xor(s, off);
  if (lane == 0) {
    float d = rsqrtf(s * kConvScale * kConvScale + 1e-8f);
    fac[wid] = d * kConvScale;
  }
}

// ---------------------------------------------------------------------------
// Kernel 4: wb[t][o][i] = bf16(conv_w[o][i][t])   (K-contiguous A operand)
// ---------------------------------------------------------------------------
__global__ void wcast_k(const float* __restrict__ cw, u16* __restrict__ wb) {
  int tid = blockIdx.x * 256 + threadIdx.x;      // o*512+i
  int o = tid >> 9, i = tid & 511;
  const float* p = cw + tid * 9;
  #pragma unroll
  for (int t = 0; t < 9; ++t) {
    __hip_bfloat16 h = __float2bfloat16(p[t]);
    wb[(t * COUT + o) * CIN + i] = *(u16*)&h;
  }
}

// ---------------------------------------------------------------------------
// Kernel 5: xs[b][pix][i] = bf16(x[b][i][pix] * style[b][i])   (NHWC transpose)
// ---------------------------------------------------------------------------
__global__ void modx_k(const float* __restrict__ x, const float* __restrict__ style,
                       u16* __restrict__ xs) {
  __shared__ float t[64][65];
  int b  = blockIdx.z;
  int it = blockIdx.y * 64;                      // cin tile base
  int pt = blockIdx.x * 64;                      // pixel tile base
  int tp = threadIdx.x & 63;
  int tr = threadIdx.x >> 6;                     // 0..3
  for (int r = tr; r < 64; r += 4) {
    int i = it + r;
    t[r][tp] = x[(b * CIN + i) * PIX + pt + tp] * style[b * CIN + i];
  }
  __syncthreads();
  for (int r = tr; r < 64; r += 4) {
    __hip_bfloat16 h = __float2bfloat16(t[tp][r]);
    xs[(size_t)(b * PIX + pt + r) * CIN + it + tp] = *(u16*)&h;
  }
}

// ---------------------------------------------------------------------------
// Kernel 6: implicit-GEMM conv. BM=BN=256, BK=32, 4-deep LDS pipeline with
// counted vmcnt (never 0 in main loop), raw s_barrier. 8 waves (2M x 4N),
// each 128x64 out via 8x4 16x16x32 MFMA. global_load_lds(16B) staging with
// XOR bank swizzle. Grid = 256 blocks = exactly 1/CU. XCD-chunked swizzle.
// ---------------------------------------------------------------------------
__launch_bounds__(512, 2)
__global__ void gemm_k(const u16* __restrict__ wb, const u16* __restrict__ xs,
                       const float* __restrict__ fac, const float* __restrict__ noise,
                       const float* __restrict__ nscale_p, const float* __restrict__ bias,
                       const float* __restrict__ zbuf, float* __restrict__ y) {
  __shared__ __align__(16) u16 Abuf[4][256 * 32];   // 64 KiB: [buf][cout_row][cin32]
  __shared__ __align__(16) u16 Bbuf[4][256 * 32];   // 64 KiB: [buf][pixel_row][cin32]

  const int tid = threadIdx.x;
  const int bid = blockIdx.x;                    // 0..255
  const int swz = (bid & 7) * 32 + (bid >> 3);   // XCD-chunked (256 % 8 == 0)
  const int mt = swz >> 7;                       // 0..1   cout tile
  const int nt = swz & 127;                      // 0..127 pixel tile
  const int b  = nt >> 4;                        // image
  const int pimg  = (nt & 15) * 256;             // pixel base within image
  const int hbase = pimg >> 6;                   // image row base (multiple of 4)

  const int lane = tid & 63;
  const int wv = tid >> 6;                       // 0..7
  const int wm = wv >> 2;                        // 0..1  (128 rows each)
  const int wn = wv & 3;                         // 0..3  (64 cols each)
  const int l15 = lane & 15, l4 = lane >> 4;

  // ---- per-thread staging geometry (row = chunk>>2; 4 x 16B slots per row) ----
  // source-slot pre-swizzle: sg = (chunk&3) ^ ((row>>1)&3) = (tid&3)^((tid>>3)&3)
  const int sg = ((tid & 3) ^ ((tid >> 3) & 3)) * 8;   // element offset
  int offA[2], hrB[2], wwB[2];
  #pragma unroll
  for (int p = 0; p < 2; ++p) {
    int row = (p * 512 + tid) >> 2;              // 0..255
    offA[p] = (mt * 256 + row) * CIN + sg;
    hrB[p]  = hbase + (row >> 6);
    wwB[p]  = row & 63;
  }

  f32x4 acc[8][4];
  #pragma unroll
  for (int i = 0; i < 8; ++i)
    #pragma unroll
    for (int j = 0; j < 4; ++j) acc[i][j] = (f32x4){0.f, 0.f, 0.f, 0.f};

  // K-step kk = tap*16 + cin_block; 144 total.  4 loads/thread per step.
  auto stage = [&](int kk, int buf) {
    const int tap = kk >> 4;
    const int i0  = (kk & 15) << 5;
    const int dy  = tap < 3 ? -1 : (tap < 6 ? 0 : 1);
    const int dx  = (tap % 3) - 1;
    const size_t tapoff = (size_t)tap * (COUT * CIN) + i0;
    #pragma unroll
    for (int p = 0; p < 2; ++p) {
      int c = p * 512 + tid;
      const u16* src = wb + tapoff + offA[p];
      __builtin_amdgcn_global_load_lds(
          (const __attribute__((address_space(1))) void*)src,
          (__attribute__((address_space(3))) void*)(&Abuf[buf][c * 8]), 16, 0, 0);
    }
    #pragma unroll
    for (int p = 0; p < 2; ++p) {
      int c = p * 512 + tid;
      int hh = hrB[p] + dy, ww = wwB[p] + dx;
      const u16* src = ((unsigned)hh < 64u && (unsigned)ww < 64u)
          ? xs + ((size_t)(b * PIX + hh * 64 + ww) * CIN + i0 + sg)
          : (const u16*)zbuf;
      __builtin_amdgcn_global_load_lds(
          (const __attribute__((address_space(1))) void*)src,
          (__attribute__((address_space(3))) void*)(&Bbuf[buf][c * 8]), 16, 0, 0);
    }
  };

  stage(0, 0); stage(1, 1); stage(2, 2);         // 12 loads in flight
  asm volatile("s_waitcnt vmcnt(8)" ::: "memory");   // tile 0 complete
  __builtin_amdgcn_s_barrier();

  const int slr = (l4 ^ ((l15 >> 1) & 3)) * 8;   // read-side swizzled slot (const/thread)

  for (int kk = 0; kk < 144; ++kk) {
    const int buf = kk & 3;
    if (kk < 141) stage(kk + 3, (kk + 3) & 3);   // 3-deep prefetch

    const u16* Ab = &Abuf[buf][0];
    const u16* Bb = &Bbuf[buf][0];
    bf16x8 af[8], bfr[4];
    #pragma unroll
    for (int mi = 0; mi < 8; ++mi) {
      int r = wm * 128 + mi * 16 + l15;
      af[mi] = *(const bf16x8*)&Ab[r * 32 + slr];
    }
    #pragma unroll
    for (int ni = 0; ni < 4; ++ni) {
      int r = wn * 64 + ni * 16 + l15;
      bfr[ni] = *(const bf16x8*)&Bb[r * 32 + slr];
    }
    #pragma unroll
    for (int mi = 0; mi < 8; ++mi)
      #pragma unroll
      for (int ni = 0; ni < 4; ++ni)
        acc[mi][ni] = __builtin_amdgcn_mfma_f32_16x16x32_bf16(af[mi], bfr[ni],
                                                              acc[mi][ni], 0, 0, 0);
    if (kk < 143) {
      const int rem = 143 - kk;
      if (rem > 2)       asm volatile("s_waitcnt vmcnt(8)" ::: "memory"); // tile kk+1 done; kk+2/kk+3 in flight
      else if (rem == 2) asm volatile("s_waitcnt vmcnt(4)" ::: "memory");
      else               asm volatile("s_waitcnt vmcnt(0)" ::: "memory");
      asm volatile("s_waitcnt lgkmcnt(0)" ::: "memory"); // reads serviced before buffer reuse
      __builtin_amdgcn_s_barrier();
    }
  }

  // Epilogue: y = lrelu(acc*fac + noise*nscale + bias) * sqrt(2)
  const float ns = nscale_p[0];
  float nz[4];
  #pragma unroll
  for (int ni = 0; ni < 4; ++ni) {
    int pix = pimg + wn * 64 + ni * 16 + l15;
    nz[ni] = noise[b * PIX + pix] * ns;
  }
  #pragma unroll
  for (int mi = 0; mi < 8; ++mi) {
    int o = mt * 256 + wm * 128 + mi * 16 + l4 * 4;
    f32x4 fv = *(const f32x4*)&fac[b * COUT + o];
    f32x4 bv = *(const f32x4*)&bias[o];
    #pragma unroll
    for (int r = 0; r < 4; ++r) {
      float* yp = y + (size_t)(b * COUT + o + r) * PIX + pimg + wn * 64 + l15;
      #pragma unroll
      for (int ni = 0; ni < 4; ++ni) {
        float v = acc[mi][ni][r] * fv[r] + nz[ni] + bv[r];
        v = (v > 0.0f ? v : 0.2f * v) * kGain;
        yp[ni * 16] = v;
      }
    }
  }
}

// ---------------------------------------------------------------------------
extern "C" void kernel_launch(void* const* d_in, const int* in_sizes, int n_in,
                              void* d_out, int out_size, void* d_ws, size_t ws_size,
                              hipStream_t stream) {
  const float* x      = (const float*)d_in[0];
  const float* w      = (const float*)d_in[1];
  const float* noise  = (const float*)d_in[2];
  const float* aff_w  = (const float*)d_in[3];
  const float* aff_b  = (const float*)d_in[4];
  const float* conv_w = (const float*)d_in[5];
  const float* nscale = (const float*)d_in[6];
  const float* bias   = (const float*)d_in[7];
  float* y = (float*)d_out;

  char* ws = (char*)d_ws;
  float* style = (float*)(ws);                          // 16 KB
  float* fac   = (float*)(ws + 16384);                  // 16 KB
  float* cw2   = (float*)(ws + 32768);                  // 1 MB
  float* zbuf  = (float*)(ws + 1081344);                // 256 B zeros
  u16*   wb    = (u16*)(ws + 1081600);                  // 4.5 MB
  u16*   xs    = (u16*)(ws + 5800192);                  // 32 MB

  style_k<<<16, 256, 0, stream>>>(w, aff_w, aff_b, style, zbuf);
  cw2_k<<<1024, 256, 0, stream>>>(conv_w, cw2);
  fac_k<<<1024, 256, 0, stream>>>(style, cw2, fac);
  wcast_k<<<1024, 256, 0, stream>>>(conv_w, wb);
  modx_k<<<dim3(64, 8, 8), 256, 0, stream>>>(x, style, xs);
  gemm_k<<<256, 512, 0, stream>>>(wb, xs, fac, noise, nscale, bias, zbuf, y);
}

// Round 3
// 200.047 us; speedup vs baseline: 1.1828x; 1.1611x over previous
//
#include <hip/hip_runtime.h>
#include <hip/hip_bf16.h>

typedef unsigned short u16;

#define BATCH 8
#define CIN 512
#define COUT 512
#define SDIM 512
#define RES 64
#define PIX (RES * RES)          // 4096
#define NKT 72                   // K-tiles of 64: 9 taps * 8 cin-blocks

__device__ __constant__ static const float kAffScale  = 0.04419417382415922f;   // 1/sqrt(512)
__device__ __constant__ static const float kConvScale = 0.014731391274719742f;  // 1/sqrt(512*9)
__device__ __constant__ static const float kGain      = 1.4142135623730951f;    // sqrt(2)

typedef __bf16 bf16x8 __attribute__((ext_vector_type(8)));
typedef float  f32x4  __attribute__((ext_vector_type(4)));

// ---------------------------------------------------------------------------
// Kernel 1: style[b][c] = (w[b] . affine_w[c]) * AFF_SCALE + affine_b[c]
// ---------------------------------------------------------------------------
__global__ void style_k(const float* __restrict__ w, const float* __restrict__ aw,
                        const float* __restrict__ ab, float* __restrict__ style,
                        float* __restrict__ zbuf) {
  int tid = blockIdx.x * 256 + threadIdx.x;      // 0..4095
  if (blockIdx.x == 0 && threadIdx.x < 64) zbuf[threadIdx.x] = 0.0f;
  int b = tid >> 9, c = tid & 511;
  const float* wp = w + b * SDIM;
  const float* ap = aw + c * SDIM;
  float s = 0.0f;
  for (int k = 0; k < SDIM; ++k) s += wp[k] * ap[k];
  style[tid] = s * kAffScale + ab[c];
}

// ---------------------------------------------------------------------------
// Kernel 2: cw2[o][i] = sum_t conv_w[o][i][t]^2
// ---------------------------------------------------------------------------
__global__ void cw2_k(const float* __restrict__ cw, float* __restrict__ cw2) {
  int tid = blockIdx.x * 256 + threadIdx.x;      // o*512+i
  const float* p = cw + tid * 9;
  float s = 0.0f;
  #pragma unroll
  for (int t = 0; t < 9; ++t) { float v = p[t]; s += v * v; }
  cw2[tid] = s;
}

// ---------------------------------------------------------------------------
// Kernel 3: fac[b][o] = CONV_SCALE * rsqrt(CONV_SCALE^2 * sum_i style^2*cw2 + 1e-8)
// ---------------------------------------------------------------------------
__global__ void fac_k(const float* __restrict__ style, const float* __restrict__ cw2,
                      float* __restrict__ fac) {
  int wid  = blockIdx.x * 4 + (threadIdx.x >> 6); // 0..4095
  int lane = threadIdx.x & 63;
  int b = wid >> 9, o = wid & 511;
  const float* st = style + b * CIN;
  const float* c2 = cw2 + o * CIN;
  float s = 0.0f;
  for (int i = lane; i < CIN; i += 64) { float sv = st[i]; s += sv * sv * c2[i]; }
  #pragma unroll
  for (int off = 32; off; off >>= 1) s += __shfl_xor(s, off);
  if (lane == 0) {
    float d = rsqrtf(s * kConvScale * kConvScale + 1e-8f);
    fac[wid] = d * kConvScale;
  }
}

// ---------------------------------------------------------------------------
// Kernel 4: wb[t][o][i] = bf16(conv_w[o][i][t])   (K-contiguous A operand)
// ---------------------------------------------------------------------------
__global__ void wcast_k(const float* __restrict__ cw, u16* __restrict__ wb) {
  int tid = blockIdx.x * 256 + threadIdx.x;      // o*512+i
  int o = tid >> 9, i = tid & 511;
  const float* p = cw + tid * 9;
  #pragma unroll
  for (int t = 0; t < 9; ++t) {
    __hip_bfloat16 h = __float2bfloat16(p[t]);
    wb[(t * COUT + o) * CIN + i] = *(u16*)&h;
  }
}

// ---------------------------------------------------------------------------
// Kernel 5: xs[b][pix][i] = bf16(x[b][i][pix] * style[b][i])   (NHWC transpose)
// ---------------------------------------------------------------------------
__global__ void modx_k(const float* __restrict__ x, const float* __restrict__ style,
                       u16* __restrict__ xs) {
  __shared__ float t[64][65];
  int b  = blockIdx.z;
  int it = blockIdx.y * 64;                      // cin tile base
  int pt = blockIdx.x * 64;                      // pixel tile base
  int tp = threadIdx.x & 63;
  int tr = threadIdx.x >> 6;                     // 0..3
  for (int r = tr; r < 64; r += 4) {
    int i = it + r;
    t[r][tp] = x[(b * CIN + i) * PIX + pt + tp] * style[b * CIN + i];
  }
  __syncthreads();
  for (int r = tr; r < 64; r += 4) {
    __hip_bfloat16 h = __float2bfloat16(t[tp][r]);
    xs[(size_t)(b * PIX + pt + r) * CIN + it + tp] = *(u16*)&h;
  }
}

// ---------------------------------------------------------------------------
// Kernel 6: implicit-GEMM conv, m201-style 8-phase schedule.
// BM=BN=256, BK=64 (2 K-slices of 32). 8 waves (2M x 4N), wave out 128x64.
// LDS: 2 dbuf x (A 256x64 + B 256x64) bf16 = 128 KiB, stored as
//   [dbuf][kh][row][4 slots of 16B], slot swizzle within-slice.
// Per K-tile: 4 phases {4-8 ds_read_b128; stage 1 K-slice quantum (2 gll16);
//   s_barrier; lgkmcnt(0); sched_barrier; setprio(1); 16 MFMA; setprio(0);
//   [vmcnt(8) at ph1/ph3]; s_barrier}. vmcnt never 0 in main loop.
// ---------------------------------------------------------------------------
__launch_bounds__(512, 2)
__global__ void gemm_k(const u16* __restrict__ wb, const u16* __restrict__ xs,
                       const float* __restrict__ fac, const float* __restrict__ noise,
                       const float* __restrict__ nscale_p, const float* __restrict__ bias,
                       const float* __restrict__ zbuf, float* __restrict__ y) {
  __shared__ __align__(16) u16 Abuf[2][16384];   // [dbuf][kh*8192 + row*32 + slot*8]
  __shared__ __align__(16) u16 Bbuf[2][16384];

  const int tid = threadIdx.x;
  const int bid = blockIdx.x;                    // 0..255
  const int swz = (bid & 7) * 32 + (bid >> 3);   // XCD-chunked (256 % 8 == 0)
  const int mt = swz >> 7;                       // 0..1   cout tile
  const int nt = swz & 127;                      // 0..127 pixel tile
  const int b  = nt >> 4;                        // image
  const int pimg  = (nt & 15) * 256;             // pixel base within image
  const int hbase = pimg >> 6;                   // image row base

  const int lane = tid & 63;
  const int wv = tid >> 6;                       // 0..7
  const int wm = wv >> 2;                        // 0..1  (128 out-rows)
  const int wn = wv & 3;                         // 0..3  (64 out-cols)
  const int l15 = lane & 15, l4 = lane >> 4;
  const int slot = (l4 ^ ((l15 >> 1) & 3)) * 8;  // swizzled 16B slot (u16 units)

  // ---- staging per-thread constants: chunk c = p*512+tid, row=c>>2, slot=c&3
  const int sg8 = (((tid & 3) ^ ((tid >> 3) & 3)) << 3);  // source cin sub-offset
  size_t offA[2]; int hr[2], wc[2];
  #pragma unroll
  for (int p = 0; p < 2; ++p) {
    int row = (p * 512 + tid) >> 2;              // 0..255
    offA[p] = (size_t)(mt * 256 + row) * CIN + sg8;
    hr[p] = hbase + (row >> 6);
    wc[p] = row & 63;
  }

  // stage one A K-slice quantum: K-tile ktx, slice kh -> dbuf[ktx&1]
  auto stA = [&](int ktx, int kh) {
    if (ktx >= NKT) ktx -= NKT;
    const int tap = ktx >> 3;
    const int i0  = (ktx & 7) << 6;
    const int d   = ktx & 1;
    const u16* basep = wb + (size_t)tap * (COUT * CIN) + i0 + kh * 32;
    #pragma unroll
    for (int p = 0; p < 2; ++p) {
      const u16* src = basep + offA[p];
      __builtin_amdgcn_global_load_lds(
          (const __attribute__((address_space(1))) void*)src,
          (__attribute__((address_space(3))) void*)(&Abuf[d][kh * 8192 + (p * 512 + tid) * 8]),
          16, 0, 0);
    }
  };
  auto stB = [&](int ktx, int kh) {
    if (ktx >= NKT) ktx -= NKT;
    const int tap = ktx >> 3;
    const int i0  = (ktx & 7) << 6;
    const int dy  = tap < 3 ? -1 : (tap < 6 ? 0 : 1);
    const int dx  = (tap - (tap < 3 ? 0 : (tap < 6 ? 3 : 6))) - 1;
    const int d   = ktx & 1;
    #pragma unroll
    for (int p = 0; p < 2; ++p) {
      int hh = hr[p] + dy, ww = wc[p] + dx;
      const u16* src = ((unsigned)hh < 64u && (unsigned)ww < 64u)
          ? xs + ((size_t)(b * PIX + hh * 64 + ww) * CIN + i0 + kh * 32 + sg8)
          : (const u16*)zbuf;
      __builtin_amdgcn_global_load_lds(
          (const __attribute__((address_space(1))) void*)src,
          (__attribute__((address_space(3))) void*)(&Bbuf[d][kh * 8192 + (p * 512 + tid) * 8]),
          16, 0, 0);
    }
  };

  f32x4 acc[8][4];
  #pragma unroll
  for (int i = 0; i < 8; ++i)
    #pragma unroll
    for (int j = 0; j < 4; ++j) acc[i][j] = (f32x4){0.f, 0.f, 0.f, 0.f};

  // Prologue: kt0 full tile + kt1 kh0; 6 quanta = 12 loads. Steady entry.
  stA(0, 0); stB(0, 0); stA(0, 1); stB(0, 1); stA(1, 0); stB(1, 0);
  asm volatile("s_waitcnt vmcnt(8)" ::: "memory");   // kt0 kh0 (A+B) landed
  __builtin_amdgcn_s_barrier();

#define LDA(mi, kh) (*(const bf16x8*)&Ab[(kh) * 8192 + (wm * 128 + (mi) * 16 + l15) * 32 + slot])
#define LDB(ni, kh) (*(const bf16x8*)&Bb[(kh) * 8192 + (wn * 64 + (ni) * 16 + l15) * 32 + slot])

  for (int kt = 0; kt < NKT; ++kt) {
    const u16* Ab = &Abuf[kt & 1][0];
    const u16* Bb = &Bbuf[kt & 1][0];
    bf16x8 bfr[4], af[4];

    // ---- phase 0: kh0 mi0-3 ----
    #pragma unroll
    for (int ni = 0; ni < 4; ++ni) bfr[ni] = LDB(ni, 0);
    #pragma unroll
    for (int j = 0; j < 4; ++j) af[j] = LDA(j, 0);
    stA(kt + 1, 1);
    __builtin_amdgcn_s_barrier();
    asm volatile("s_waitcnt lgkmcnt(0)" ::: "memory");
    __builtin_amdgcn_sched_barrier(0);
    __builtin_amdgcn_s_setprio(1);
    #pragma unroll
    for (int j = 0; j < 4; ++j)
      #pragma unroll
      for (int ni = 0; ni < 4; ++ni)
        acc[j][ni] = __builtin_amdgcn_mfma_f32_16x16x32_bf16(af[j], bfr[ni], acc[j][ni], 0, 0, 0);
    __builtin_amdgcn_s_setprio(0);
    __builtin_amdgcn_s_barrier();

    // ---- phase 1: kh0 mi4-7 ----
    #pragma unroll
    for (int j = 0; j < 4; ++j) af[j] = LDA(4 + j, 0);
    stB(kt + 1, 1);
    __builtin_amdgcn_s_barrier();
    asm volatile("s_waitcnt lgkmcnt(0)" ::: "memory");
    __builtin_amdgcn_sched_barrier(0);
    __builtin_amdgcn_s_setprio(1);
    #pragma unroll
    for (int j = 0; j < 4; ++j)
      #pragma unroll
      for (int ni = 0; ni < 4; ++ni)
        acc[4 + j][ni] = __builtin_amdgcn_mfma_f32_16x16x32_bf16(af[j], bfr[ni], acc[4 + j][ni], 0, 0, 0);
    __builtin_amdgcn_s_setprio(0);
    asm volatile("s_waitcnt vmcnt(8)" ::: "memory");   // kt's kh1 slices landed
    __builtin_amdgcn_s_barrier();

    // ---- phase 2: kh1 mi0-3 ----
    #pragma unroll
    for (int ni = 0; ni < 4; ++ni) bfr[ni] = LDB(ni, 1);
    #pragma unroll
    for (int j = 0; j < 4; ++j) af[j] = LDA(j, 1);
    stA(kt + 2, 0);
    __builtin_amdgcn_s_barrier();
    asm volatile("s_waitcnt lgkmcnt(0)" ::: "memory");
    __builtin_amdgcn_sched_barrier(0);
    __builtin_amdgcn_s_setprio(1);
    #pragma unroll
    for (int j = 0; j < 4; ++j)
      #pragma unroll
      for (int ni = 0; ni < 4; ++ni)
        acc[j][ni] = __builtin_amdgcn_mfma_f32_16x16x32_bf16(af[j], bfr[ni], acc[j][ni], 0, 0, 0);
    __builtin_amdgcn_s_setprio(0);
    __builtin_amdgcn_s_barrier();

    // ---- phase 3: kh1 mi4-7 ----
    #pragma unroll
    for (int j = 0; j < 4; ++j) af[j] = LDA(4 + j, 1);
    stB(kt + 2, 0);
    __builtin_amdgcn_s_barrier();
    asm volatile("s_waitcnt lgkmcnt(0)" ::: "memory");
    __builtin_amdgcn_sched_barrier(0);
    __builtin_amdgcn_s_setprio(1);
    #pragma unroll
    for (int j = 0; j < 4; ++j)
      #pragma unroll
      for (int ni = 0; ni < 4; ++ni)
        acc[4 + j][ni] = __builtin_amdgcn_mfma_f32_16x16x32_bf16(af[j], bfr[ni], acc[4 + j][ni], 0, 0, 0);
    __builtin_amdgcn_s_setprio(0);
    asm volatile("s_waitcnt vmcnt(8)" ::: "memory");   // kt+1's kh0 slices landed
    __builtin_amdgcn_s_barrier();
  }
#undef LDA
#undef LDB

  // Epilogue: y = lrelu(acc*fac + noise*nscale + bias) * sqrt(2)
  const float ns = nscale_p[0];
  float nz[4];
  #pragma unroll
  for (int ni = 0; ni < 4; ++ni) {
    int pix = pimg + wn * 64 + ni * 16 + l15;
    nz[ni] = noise[b * PIX + pix] * ns;
  }
  #pragma unroll
  for (int mi = 0; mi < 8; ++mi) {
    int o = mt * 256 + wm * 128 + mi * 16 + l4 * 4;
    f32x4 fv = *(const f32x4*)&fac[b * COUT + o];
    f32x4 bv = *(const f32x4*)&bias[o];
    #pragma unroll
    for (int r = 0; r < 4; ++r) {
      float* yp = y + (size_t)(b * COUT + o + r) * PIX + pimg + wn * 64 + l15;
      #pragma unroll
      for (int ni = 0; ni < 4; ++ni) {
        float v = acc[mi][ni][r] * fv[r] + nz[ni] + bv[r];
        v = (v > 0.0f ? v : 0.2f * v) * kGain;
        yp[ni * 16] = v;
      }
    }
  }
}

// ---------------------------------------------------------------------------
extern "C" void kernel_launch(void* const* d_in, const int* in_sizes, int n_in,
                              void* d_out, int out_size, void* d_ws, size_t ws_size,
                              hipStream_t stream) {
  const float* x      = (const float*)d_in[0];
  const float* w      = (const float*)d_in[1];
  const float* noise  = (const float*)d_in[2];
  const float* aff_w  = (const float*)d_in[3];
  const float* aff_b  = (const float*)d_in[4];
  const float* conv_w = (const float*)d_in[5];
  const float* nscale = (const float*)d_in[6];
  const float* bias   = (const float*)d_in[7];
  float* y = (float*)d_out;

  char* ws = (char*)d_ws;
  float* style = (float*)(ws);                          // 16 KB
  float* fac   = (float*)(ws + 16384);                  // 16 KB
  float* cw2   = (float*)(ws + 32768);                  // 1 MB
  float* zbuf  = (float*)(ws + 1081344);                // 256 B zeros
  u16*   wb    = (u16*)(ws + 1081600);                  // 4.5 MB
  u16*   xs    = (u16*)(ws + 5800192);                  // 32 MB

  style_k<<<16, 256, 0, stream>>>(w, aff_w, aff_b, style, zbuf);
  cw2_k<<<1024, 256, 0, stream>>>(conv_w, cw2);
  fac_k<<<1024, 256, 0, stream>>>(style, cw2, fac);
  wcast_k<<<1024, 256, 0, stream>>>(conv_w, wb);
  modx_k<<<dim3(64, 8, 8), 256, 0, stream>>>(x, style, xs);
  gemm_k<<<256, 512, 0, stream>>>(wb, xs, fac, noise, nscale, bias, zbuf, y);
}